// Round 8
// baseline (137.359 us; speedup 1.0000x reference)
//
#include <hip/hip_runtime.h>

// Problem constants: bt=4, nv=20000, nf=40000, H=W=256, S=2048
#define BT   4
#define NV   20000
#define NF   40000
#define SMP  2048
#define NPIX (BT * 256 * 256)
#define NVG  (BT * NV)            // 80000
#define NCH  256                  // vertex chunks per batch
#define NBLK (BT * NCH)           // 1024 blocks = 4/CU = 4 waves/SIMD
#define NTH  256
#define CHUNK 79                  // ceil(NV/NCH)
#define P    8                    // samples per thread (256*8 = 2048)
#define MAGIC 0x5ACE1234u         // "visible" marker; ws pre-state never matters

// Order-preserving float<->uint encoding (q can be negative).
__device__ __forceinline__ unsigned int enc_f32(float f) {
    unsigned int u = __float_as_uint(f);
    return (u & 0x80000000u) ? ~u : (u | 0x80000000u);
}
__device__ __forceinline__ float dec_f32(unsigned int k) {
    unsigned int u = (k & 0x80000000u) ? (k & 0x7FFFFFFFu) : ~k;
    return __uint_as_float(u);
}

// 1) visibility scatter (4 pixels/thread -> face -> 3 verts) + side-init of
//    minKeys/flags/cnt for the next kernel (kernel boundary orders + flushes).
__global__ __launch_bounds__(NTH) void
vis_k(const int4* __restrict__ p2f,
      const int* __restrict__ faces,
      unsigned int* __restrict__ visible,
      unsigned int* __restrict__ minKeys,
      unsigned int* __restrict__ flags,
      unsigned int* __restrict__ cnt) {
    int p = blockIdx.x * blockDim.x + threadIdx.x;   // < NPIX/4 = 65536
    // side-init (no separate init kernel)
    if (p < BT * SMP) minKeys[p] = 0xFFFFFFFFu;
    if (p < BT)       flags[p]   = 0u;
    if (p == BT)      cnt[0]     = 0u;

    int4 f4 = p2f[p];
    int fs[4] = {f4.x, f4.y, f4.z, f4.w};
    #pragma unroll
    for (int k = 0; k < 4; ++k) {
        int fi = fs[k];
        if (fi >= 0) {
            int b    = fi / NF;
            int base = fi * 3;
            int off  = b * NV;
            visible[faces[base + 0] + off] = MAGIC;   // idempotent racy
            visible[faces[base + 1] + off] = MAGIC;
            visible[faces[base + 2] + off] = MAGIC;
        }
    }
}

// 2) mega: pack own chunk into LDS, P=8 min loop with 1-deep register
//    prefetch, filtered atomicMin on encoded keys; last-arriving block
//    (ticket) finalizes the loss.
__global__ __launch_bounds__(NTH) void
mega_k(const float*  __restrict__ verts,
       const float4* __restrict__ bds,
       const unsigned int* __restrict__ visible,
       unsigned int* __restrict__ flags,
       unsigned int* __restrict__ minKeys,
       unsigned int* __restrict__ cnt,
       float*        __restrict__ out) {
    __shared__ float4 shv[CHUNK + 1];   // +1: prefetch may read one past
    __shared__ bool   lastBlk;
    __shared__ float  part[4];
    __shared__ unsigned int fbb[BT];

    const int tid = threadIdx.x;
    const int b   = blockIdx.z;
    const int c   = blockIdx.x;
    const int v0  = c * CHUNK;
    const int cntv = max(0, min(CHUNK, NV - v0));   // 79 (or short/0 tail)

    // pack own chunk straight into LDS
    if (tid <= cntv) {                  // tid==cntv zeroes the pad slot
        if (tid < cntv) {
            int vi = b * NV + v0 + tid;
            float x = verts[3 * vi + 0];
            float y = verts[3 * vi + 1];
            float z = verts[3 * vi + 2];
            float w;
            if (visible[vi] == MAGIC) {
                w = x * x + y * y + z * z;  // q = |v|^2 - 2<p,v>; +|p|^2 later
            } else {
                w = 1e30f;                  // never wins the min
                atomicOr(&flags[b], 1u);    // device-scope, rare
            }
            shv[tid] = make_float4(-2.f * x, -2.f * y, -2.f * z, w);
        } else {
            shv[tid] = make_float4(0.f, 0.f, 0.f, 1e30f);  // pad
        }
    }

    float px[P], py[P], pz[P], mn[P];
    #pragma unroll
    for (int u = 0; u < P; ++u) {
        float4 p = bds[b * SMP + u * NTH + tid];
        px[u] = p.x; py[u] = p.y; pz[u] = p.z;
        mn[u] = 3.0e38f;
    }
    __syncthreads();

    if (cntv > 0) {
        float4 v = shv[0];
        #pragma unroll 4
        for (int j = 0; j < cntv; ++j) {
            float4 vn = shv[j + 1];         // prefetch next (pad-safe)
            #pragma unroll
            for (int u = 0; u < P; ++u) {
                float q = fmaf(px[u], v.x,
                          fmaf(py[u], v.y,
                          fmaf(pz[u], v.z, v.w)));
                mn[u] = fminf(mn[u], q);
            }
            v = vn;
        }
        // filtered atomicMin: keys only decrease; a (possibly stale) plain
        // load is >= the true current value, so skipping when we can't
        // improve is always safe.
        #pragma unroll
        for (int u = 0; u < P; ++u) {
            int idx = b * SMP + u * NTH + tid;
            unsigned int e = enc_f32(mn[u]);
            if (e < minKeys[idx]) atomicMin(&minKeys[idx], e);
        }
    }

    // ticket: last block to finish does the final reduction
    __syncthreads();
    if (tid == 0) {
        __threadfence();
        lastBlk = (atomicAdd(cnt, 1u) == NBLK - 1);
    }
    __syncthreads();
    if (!lastBlk) return;

    // final: coherent atomic reads of keys, +|p|^2, penalty clamp, masked sum
    if (tid < BT) fbb[tid] = atomicOr(&flags[tid], 0u);  // coherent read
    __syncthreads();
    float sum = 0.0f;
    #pragma unroll
    for (int bb = 0; bb < BT; ++bb) {
        unsigned int fb = fbb[bb];
        for (int j = 0; j < SMP; j += NTH) {
            int i = bb * SMP + j + tid;
            unsigned int k = atomicAdd(&minKeys[i], 0u);  // coherent read
            float4 p = bds[i];
            float bs = fmaf(p.x, p.x, fmaf(p.y, p.y, p.z * p.z));
            float mnv = dec_f32(k) + bs;
            if (fb) mnv = fminf(mnv, 1000.0f);        // exact MASK_PENALTY
            sum = fmaf(mnv, p.w, sum);                // p.w = sample mask
        }
    }
    #pragma unroll
    for (int o = 32; o > 0; o >>= 1) sum += __shfl_down(sum, o, 64);
    if ((tid & 63) == 0) part[tid >> 6] = sum;
    __syncthreads();
    if (tid == 0)
        out[0] = (part[0] + part[1] + part[2] + part[3]) / (float)BT;
}

extern "C" void kernel_launch(void* const* d_in, const int* in_sizes, int n_in,
                              void* d_out, int out_size, void* d_ws, size_t ws_size,
                              hipStream_t stream) {
    const float*  verts = (const float*)d_in[0];   // (4,20000,3) f32
    const float4* bds   = (const float4*)d_in[1];  // (4,2048,4)  f32
    const int*    faces = (const int*)d_in[2];     // (4,40000,3) int
    const int4*   p2f   = (const int4*)d_in[3];    // (4,256,256,1) int
    float*        out   = (float*)d_out;

    char* ws = (char*)d_ws;
    unsigned int* visible = (unsigned int*)ws;                // 320,000 B
    unsigned int* minKeys = (unsigned int*)(ws + 320000);     //  32,768 B
    unsigned int* flags   = (unsigned int*)(ws + 352768);     //      16 B
    unsigned int* cnt     = (unsigned int*)(ws + 352784);     //       4 B

    vis_k<<<(NPIX / 4) / NTH, NTH, 0, stream>>>(
        (const int4*)p2f, faces, visible, minKeys, flags, cnt);
    mega_k<<<dim3(NCH, 1, BT), NTH, 0, stream>>>(
        verts, bds, visible, flags, minKeys, cnt, out);
}

// Round 9
// 114.007 us; speedup vs baseline: 1.2048x; 1.2048x over previous
//
#include <hip/hip_runtime.h>

// Problem constants: bt=4, nv=20000, nf=40000, H=W=256, S=2048
#define BT   4
#define NV   20000
#define NF   40000
#define SMP  2048
#define NPIX (BT * 256 * 256)
#define NVG  (BT * NV)            // 80000
#define NCH  128                  // vertex chunks per batch (R6 sweet spot)
#define NBLK (BT * NCH)           // 512 blocks = 2/CU = 2 waves/SIMD
#define NTH  256
#define CHUNK 157                 // ceil(NV/NCH); last chunk = 61
#define P    8                    // samples per thread (256*8 = 2048)
#define MAGIC 0x5ACE1234u         // "visible" marker; ws pre-state never matters

// Order-preserving float<->uint encoding (q can be negative).
__device__ __forceinline__ unsigned int enc_f32(float f) {
    unsigned int u = __float_as_uint(f);
    return (u & 0x80000000u) ? ~u : (u | 0x80000000u);
}
__device__ __forceinline__ float dec_f32(unsigned int k) {
    unsigned int u = (k & 0x80000000u) ? (k & 0x7FFFFFFFu) : ~k;
    return __uint_as_float(u);
}

// 1) visibility scatter (4 pixels/thread -> face -> 3 verts) + side-init of
//    minKeys/flags/cnt for the next kernel (kernel boundary orders + flushes).
__global__ __launch_bounds__(NTH) void
vis_k(const int4* __restrict__ p2f,
      const int* __restrict__ faces,
      unsigned int* __restrict__ visible,
      unsigned int* __restrict__ minKeys,
      unsigned int* __restrict__ flags,
      unsigned int* __restrict__ cnt) {
    int p = blockIdx.x * blockDim.x + threadIdx.x;   // < NPIX/4 = 65536
    // side-init (no separate init kernel)
    if (p < BT * SMP) minKeys[p] = 0xFFFFFFFFu;
    if (p < BT)       flags[p]   = 0u;
    if (p == BT)      cnt[0]     = 0u;

    int4 f4 = p2f[p];
    int fs[4] = {f4.x, f4.y, f4.z, f4.w};
    #pragma unroll
    for (int k = 0; k < 4; ++k) {
        int fi = fs[k];
        if (fi >= 0) {
            int b    = fi / NF;
            int base = fi * 3;
            int off  = b * NV;
            visible[faces[base + 0] + off] = MAGIC;   // idempotent racy
            visible[faces[base + 1] + off] = MAGIC;
            visible[faces[base + 2] + off] = MAGIC;
        }
    }
}

// 2) mega: pack own chunk into LDS, P=8 min loop with 1-deep register
//    prefetch, filtered atomicMin on encoded keys; last-arriving block
//    (ticket) finalizes the loss.
__global__ __launch_bounds__(NTH) void
mega_k(const float*  __restrict__ verts,
       const float4* __restrict__ bds,
       const unsigned int* __restrict__ visible,
       unsigned int* __restrict__ flags,
       unsigned int* __restrict__ minKeys,
       unsigned int* __restrict__ cnt,
       float*        __restrict__ out) {
    __shared__ float4 shv[CHUNK + 1];   // +1: prefetch reads one past
    __shared__ bool   lastBlk;
    __shared__ float  part[4];
    __shared__ unsigned int fbb[BT];

    const int tid = threadIdx.x;
    const int b   = blockIdx.z;
    const int c   = blockIdx.x;
    const int v0  = c * CHUNK;
    const int cntv = min(CHUNK, NV - v0);   // 157 or 61 (last)

    // pack own chunk straight into LDS (no global packed[] round trip)
    if (tid <= cntv) {                  // tid==cntv fills the pad slot
        if (tid < cntv) {
            int vi = b * NV + v0 + tid;
            float x = verts[3 * vi + 0];
            float y = verts[3 * vi + 1];
            float z = verts[3 * vi + 2];
            float w;
            if (visible[vi] == MAGIC) {
                w = x * x + y * y + z * z;  // q = |v|^2 - 2<p,v>; +|p|^2 later
            } else {
                w = 1e30f;                  // never wins the min
                atomicOr(&flags[b], 1u);    // device-scope, rare
            }
            shv[tid] = make_float4(-2.f * x, -2.f * y, -2.f * z, w);
        } else {
            shv[tid] = make_float4(0.f, 0.f, 0.f, 1e30f);  // pad
        }
    }

    float px[P], py[P], pz[P], mn[P];
    #pragma unroll
    for (int u = 0; u < P; ++u) {
        float4 p = bds[b * SMP + u * NTH + tid];
        px[u] = p.x; py[u] = p.y; pz[u] = p.z;
        mn[u] = 3.0e38f;
    }
    __syncthreads();

    {
        float4 v = shv[0];
        #pragma unroll 4
        for (int j = 0; j < cntv; ++j) {
            float4 vn = shv[j + 1];         // 1-deep prefetch (pad-safe)
            #pragma unroll
            for (int u = 0; u < P; ++u) {
                float q = fmaf(px[u], v.x,
                          fmaf(py[u], v.y,
                          fmaf(pz[u], v.z, v.w)));
                mn[u] = fminf(mn[u], q);
            }
            v = vn;
        }
    }

    // filtered atomicMin: keys only decrease; a (possibly stale) plain load
    // is >= the true current value, so skipping when we can't improve is
    // always safe. Cuts ~1M device-scope atomics to ~tens of thousands.
    #pragma unroll
    for (int u = 0; u < P; ++u) {
        int idx = b * SMP + u * NTH + tid;
        unsigned int e = enc_f32(mn[u]);
        if (e < minKeys[idx]) atomicMin(&minKeys[idx], e);
    }

    // ticket: last block to finish does the final reduction
    __syncthreads();
    if (tid == 0) {
        __threadfence();
        lastBlk = (atomicAdd(cnt, 1u) == NBLK - 1);
    }
    __syncthreads();
    if (!lastBlk) return;

    // final: coherent atomic reads of keys, +|p|^2, penalty clamp, masked sum
    if (tid < BT) fbb[tid] = atomicOr(&flags[tid], 0u);  // coherent read
    __syncthreads();
    float sum = 0.0f;
    #pragma unroll
    for (int bb = 0; bb < BT; ++bb) {
        unsigned int fb = fbb[bb];
        for (int j = 0; j < SMP; j += NTH) {
            int i = bb * SMP + j + tid;
            unsigned int k = atomicAdd(&minKeys[i], 0u);  // coherent read
            float4 p = bds[i];
            float bs = fmaf(p.x, p.x, fmaf(p.y, p.y, p.z * p.z));
            float mnv = dec_f32(k) + bs;
            if (fb) mnv = fminf(mnv, 1000.0f);        // exact MASK_PENALTY
            sum = fmaf(mnv, p.w, sum);                // p.w = sample mask
        }
    }
    #pragma unroll
    for (int o = 32; o > 0; o >>= 1) sum += __shfl_down(sum, o, 64);
    if ((tid & 63) == 0) part[tid >> 6] = sum;
    __syncthreads();
    if (tid == 0)
        out[0] = (part[0] + part[1] + part[2] + part[3]) / (float)BT;
}

extern "C" void kernel_launch(void* const* d_in, const int* in_sizes, int n_in,
                              void* d_out, int out_size, void* d_ws, size_t ws_size,
                              hipStream_t stream) {
    const float*  verts = (const float*)d_in[0];   // (4,20000,3) f32
    const float4* bds   = (const float4*)d_in[1];  // (4,2048,4)  f32
    const int*    faces = (const int*)d_in[2];     // (4,40000,3) int
    const int4*   p2f   = (const int4*)d_in[3];    // (4,256,256,1) int
    float*        out   = (float*)d_out;

    char* ws = (char*)d_ws;
    unsigned int* visible = (unsigned int*)ws;                // 320,000 B
    unsigned int* minKeys = (unsigned int*)(ws + 320000);     //  32,768 B
    unsigned int* flags   = (unsigned int*)(ws + 352768);     //      16 B
    unsigned int* cnt     = (unsigned int*)(ws + 352784);     //       4 B

    vis_k<<<(NPIX / 4) / NTH, NTH, 0, stream>>>(
        (const int4*)p2f, faces, visible, minKeys, flags, cnt);
    mega_k<<<dim3(NCH, 1, BT), NTH, 0, stream>>>(
        verts, bds, visible, flags, minKeys, cnt, out);
}

// Round 10
// 99.956 us; speedup vs baseline: 1.3742x; 1.1406x over previous
//
#include <hip/hip_runtime.h>

// Problem constants: bt=4, nv=20000, nf=40000, H=W=256, S=2048
#define BT   4
#define NV   20000
#define NF   40000
#define SMP  2048
#define NPIX (BT * 256 * 256)
#define NVG  (BT * NV)            // 80000
#define NCH  128                  // vertex chunks per batch
#define NBLK (BT * NCH)           // 512 blocks = 2/CU
#define NTH  512                  // 8 waves/block -> 4 waves/SIMD resident
#define CHUNK 157                 // ceil(NV/NCH); last chunk = 61
#define P    4                    // samples per thread (512*4 = 2048)
#define MAGIC 0x5ACE1234u         // "visible" marker; ws pre-state never matters

// Order-preserving float<->uint encoding (q can be negative).
__device__ __forceinline__ unsigned int enc_f32(float f) {
    unsigned int u = __float_as_uint(f);
    return (u & 0x80000000u) ? ~u : (u | 0x80000000u);
}
__device__ __forceinline__ float dec_f32(unsigned int k) {
    unsigned int u = (k & 0x80000000u) ? (k & 0x7FFFFFFFu) : ~k;
    return __uint_as_float(u);
}

// 1) visibility scatter (1 pixel/thread for max latency-hiding occupancy)
//    + side-init of minKeys/flags (kernel boundary orders + flushes).
__global__ __launch_bounds__(256) void
vis_k(const int* __restrict__ p2f,
      const int* __restrict__ faces,
      unsigned int* __restrict__ visible,
      unsigned int* __restrict__ minKeys,
      unsigned int* __restrict__ flags) {
    int p = blockIdx.x * blockDim.x + threadIdx.x;   // < NPIX
    if (p < BT * SMP) minKeys[p] = 0xFFFFFFFFu;
    if (p < BT)       flags[p]   = 0u;

    int fi = p2f[p];
    if (fi >= 0) {
        int b    = fi / NF;
        int base = fi * 3;
        int off  = b * NV;
        visible[faces[base + 0] + off] = MAGIC;   // idempotent racy
        visible[faces[base + 1] + off] = MAGIC;
        visible[faces[base + 2] + off] = MAGIC;
    }
}

// 2) mega: pack own chunk into LDS, P=4 min loop with 1-deep register
//    prefetch, filtered atomicMin on encoded keys. No fence, no ticket --
//    finalization moved to red_k (dispatch boundary provides visibility).
__global__ __launch_bounds__(NTH) void
mega_k(const float*  __restrict__ verts,
       const float4* __restrict__ bds,
       const unsigned int* __restrict__ visible,
       unsigned int* __restrict__ flags,
       unsigned int* __restrict__ minKeys) {
    __shared__ float4 shv[CHUNK + 1];   // +1: prefetch reads one past

    const int tid = threadIdx.x;
    const int b   = blockIdx.z;
    const int c   = blockIdx.x;
    const int v0  = c * CHUNK;
    const int cntv = min(CHUNK, NV - v0);   // 157 or 61 (last)

    // pack own chunk straight into LDS; ballot-elect one flag-atomic per wave
    bool invis = false;
    if (tid <= cntv) {
        if (tid < cntv) {
            int vi = b * NV + v0 + tid;
            float x = verts[3 * vi + 0];
            float y = verts[3 * vi + 1];
            float z = verts[3 * vi + 2];
            invis = (visible[vi] != MAGIC);
            float w = invis ? 1e30f : (x * x + y * y + z * z);
            shv[tid] = make_float4(-2.f * x, -2.f * y, -2.f * z, w);
        } else {
            shv[tid] = make_float4(0.f, 0.f, 0.f, 1e30f);  // pad slot
        }
    }
    {
        unsigned long long m = __ballot(invis);
        if (m != 0ull && (int)(tid & 63) == __ffsll((long long)m) - 1)
            atomicOr(&flags[b], 1u);     // <=1 device atomic per wave
    }

    float px[P], py[P], pz[P], mn[P];
    #pragma unroll
    for (int u = 0; u < P; ++u) {
        float4 p = bds[b * SMP + u * NTH + tid];
        px[u] = p.x; py[u] = p.y; pz[u] = p.z;
        mn[u] = 3.0e38f;
    }
    __syncthreads();

    {
        float4 v = shv[0];
        #pragma unroll 4
        for (int j = 0; j < cntv; ++j) {
            float4 vn = shv[j + 1];         // 1-deep prefetch (pad-safe)
            #pragma unroll
            for (int u = 0; u < P; ++u) {
                float q = fmaf(px[u], v.x,
                          fmaf(py[u], v.y,
                          fmaf(pz[u], v.z, v.w)));  // |v|^2 - 2<p,v>
                mn[u] = fminf(mn[u], q);
            }
            v = vn;
        }
    }

    // filtered atomicMin: keys only decrease; a (possibly stale) plain load
    // is >= the true current value, so skipping when we can't improve is
    // always safe.
    #pragma unroll
    for (int u = 0; u < P; ++u) {
        int idx = b * SMP + u * NTH + tid;
        unsigned int e = enc_f32(mn[u]);
        if (e < minKeys[idx]) atomicMin(&minKeys[idx], e);
    }
}

// 3) final: single block, 1024 threads; +|p|^2, penalty clamp, masked sum.
//    Dispatch boundary makes all atomicMin results + flags visible.
__global__ __launch_bounds__(1024) void
red_k(const unsigned int* __restrict__ minKeys,
      const float4* __restrict__ bds,
      const unsigned int* __restrict__ flags,
      float* __restrict__ out) {
    const int tid = threadIdx.x;
    float sum = 0.0f;
    #pragma unroll
    for (int k = 0; k < (BT * SMP) / 1024; ++k) {
        int i = k * 1024 + tid;
        int b = i >> 11;
        float4 p = bds[i];
        float bs = fmaf(p.x, p.x, fmaf(p.y, p.y, p.z * p.z));
        float mnv = dec_f32(minKeys[i]) + bs;
        if (flags[b]) mnv = fminf(mnv, 1000.0f);   // exact MASK_PENALTY
        sum = fmaf(mnv, p.w, sum);                 // p.w = sample mask
    }
    #pragma unroll
    for (int o = 32; o > 0; o >>= 1) sum += __shfl_down(sum, o, 64);
    __shared__ float part[16];
    if ((tid & 63) == 0) part[tid >> 6] = sum;
    __syncthreads();
    if (tid == 0) {
        float t = 0.0f;
        #pragma unroll
        for (int i = 0; i < 16; ++i) t += part[i];
        out[0] = t / (float)BT;
    }
}

extern "C" void kernel_launch(void* const* d_in, const int* in_sizes, int n_in,
                              void* d_out, int out_size, void* d_ws, size_t ws_size,
                              hipStream_t stream) {
    const float*  verts = (const float*)d_in[0];   // (4,20000,3) f32
    const float4* bds   = (const float4*)d_in[1];  // (4,2048,4)  f32
    const int*    faces = (const int*)d_in[2];     // (4,40000,3) int
    const int*    p2f   = (const int*)d_in[3];     // (4,256,256,1) int
    float*        out   = (float*)d_out;

    char* ws = (char*)d_ws;
    unsigned int* visible = (unsigned int*)ws;                // 320,000 B
    unsigned int* minKeys = (unsigned int*)(ws + 320000);     //  32,768 B
    unsigned int* flags   = (unsigned int*)(ws + 352768);     //      16 B

    vis_k<<<NPIX / 256, 256, 0, stream>>>(
        p2f, faces, visible, minKeys, flags);
    mega_k<<<dim3(NCH, 1, BT), NTH, 0, stream>>>(
        verts, bds, visible, flags, minKeys);
    red_k<<<1, 1024, 0, stream>>>(minKeys, bds, flags, out);
}

// Round 11
// 95.638 us; speedup vs baseline: 1.4362x; 1.0451x over previous
//
#include <hip/hip_runtime.h>

// Problem constants: bt=4, nv=20000, nf=40000, H=W=256, S=2048
#define BT   4
#define NV   20000
#define NF   40000
#define SMP  2048
#define NPIX (BT * 256 * 256)
#define NVG  (BT * NV)            // 80000
#define NCH  128                  // vertex chunks per batch
#define NBLK (BT * NCH)           // 512 blocks = 2/CU
#define NTH  1024                 // 16 waves/block -> 8 waves/SIMD (max occ)
#define CHUNK 157                 // ceil(NV/NCH); last chunk = 61
#define P    2                    // samples per thread (1024*2 = 2048)
#define MAGIC 0x5ACE1234u         // "visible" marker; ws pre-state never matters
#define REDB 8                    // red_k blocks

// Order-preserving float<->uint encoding (q can be negative).
__device__ __forceinline__ unsigned int enc_f32(float f) {
    unsigned int u = __float_as_uint(f);
    return (u & 0x80000000u) ? ~u : (u | 0x80000000u);
}
__device__ __forceinline__ float dec_f32(unsigned int k) {
    unsigned int u = (k & 0x80000000u) ? (k & 0x7FFFFFFFu) : ~k;
    return __uint_as_float(u);
}

// 1) visibility scatter (1 pixel/thread) + side-init of minKeys/flags/out
//    (kernel boundary orders + flushes before consumers).
__global__ __launch_bounds__(256) void
vis_k(const int* __restrict__ p2f,
      const int* __restrict__ faces,
      unsigned int* __restrict__ visible,
      unsigned int* __restrict__ minKeys,
      unsigned int* __restrict__ flags,
      float* __restrict__ out) {
    int p = blockIdx.x * blockDim.x + threadIdx.x;   // < NPIX
    if (p < BT * SMP) minKeys[p] = 0xFFFFFFFFu;
    if (p < BT)       flags[p]   = 0u;
    if (p == BT)      out[0]     = 0.0f;             // for red_k atomicAdd

    int fi = p2f[p];
    if (fi >= 0) {
        int b    = fi / NF;
        int base = fi * 3;
        int off  = b * NV;
        visible[faces[base + 0] + off] = MAGIC;   // idempotent racy
        visible[faces[base + 1] + off] = MAGIC;
        visible[faces[base + 2] + off] = MAGIC;
    }
}

// 2) mega: pack own chunk into LDS, P=2 min loop with 1-deep register
//    prefetch, filtered atomicMin on encoded keys. No fence/ticket --
//    visibility to red_k via dispatch boundary.
__global__ __launch_bounds__(NTH) void
mega_k(const float*  __restrict__ verts,
       const float4* __restrict__ bds,
       const unsigned int* __restrict__ visible,
       unsigned int* __restrict__ flags,
       unsigned int* __restrict__ minKeys) {
    __shared__ float4 shv[CHUNK + 1];   // +1: prefetch reads one past

    const int tid = threadIdx.x;
    const int b   = blockIdx.z;
    const int c   = blockIdx.x;
    const int v0  = c * CHUNK;
    const int cntv = min(CHUNK, NV - v0);   // 157 or 61 (last)

    // pack own chunk straight into LDS; ballot-elect one flag-atomic per wave
    bool invis = false;
    if (tid <= cntv) {
        if (tid < cntv) {
            int vi = b * NV + v0 + tid;
            float x = verts[3 * vi + 0];
            float y = verts[3 * vi + 1];
            float z = verts[3 * vi + 2];
            invis = (visible[vi] != MAGIC);
            float w = invis ? 1e30f : (x * x + y * y + z * z);
            shv[tid] = make_float4(-2.f * x, -2.f * y, -2.f * z, w);
        } else {
            shv[tid] = make_float4(0.f, 0.f, 0.f, 1e30f);  // pad slot
        }
    }
    {
        unsigned long long m = __ballot(invis);
        if (m != 0ull && (int)(tid & 63) == __ffsll((long long)m) - 1)
            atomicOr(&flags[b], 1u);     // <=1 device atomic per wave
    }

    float px[P], py[P], pz[P], mn[P];
    #pragma unroll
    for (int u = 0; u < P; ++u) {
        float4 p = bds[b * SMP + u * NTH + tid];
        px[u] = p.x; py[u] = p.y; pz[u] = p.z;
        mn[u] = 3.0e38f;
    }
    __syncthreads();

    {
        float4 v = shv[0];
        #pragma unroll 4
        for (int j = 0; j < cntv; ++j) {
            float4 vn = shv[j + 1];         // 1-deep prefetch (pad-safe)
            #pragma unroll
            for (int u = 0; u < P; ++u) {
                float q = fmaf(px[u], v.x,
                          fmaf(py[u], v.y,
                          fmaf(pz[u], v.z, v.w)));  // |v|^2 - 2<p,v>
                mn[u] = fminf(mn[u], q);
            }
            v = vn;
        }
    }

    // filtered atomicMin: keys only decrease; a (possibly stale) plain load
    // is >= the true current value, so skipping when we can't improve is
    // always safe.
    #pragma unroll
    for (int u = 0; u < P; ++u) {
        int idx = b * SMP + u * NTH + tid;
        unsigned int e = enc_f32(mn[u]);
        if (e < minKeys[idx]) atomicMin(&minKeys[idx], e);
    }
}

// 3) final: 8 blocks x 1024 threads; +|p|^2, penalty clamp, masked sum,
//    one float atomicAdd per block into pre-zeroed out[0].
__global__ __launch_bounds__(1024) void
red_k(const unsigned int* __restrict__ minKeys,
      const float4* __restrict__ bds,
      const unsigned int* __restrict__ flags,
      float* __restrict__ out) {
    const int tid = threadIdx.x;
    const int i   = blockIdx.x * 1024 + tid;     // 0..8191
    const int b   = i >> 11;
    float4 p = bds[i];
    float bs = fmaf(p.x, p.x, fmaf(p.y, p.y, p.z * p.z));
    float mnv = dec_f32(minKeys[i]) + bs;
    if (flags[b]) mnv = fminf(mnv, 1000.0f);     // exact MASK_PENALTY
    float sum = mnv * p.w;                       // p.w = sample mask

    #pragma unroll
    for (int o = 32; o > 0; o >>= 1) sum += __shfl_down(sum, o, 64);
    __shared__ float part[16];
    if ((tid & 63) == 0) part[tid >> 6] = sum;
    __syncthreads();
    if (tid == 0) {
        float t = 0.0f;
        #pragma unroll
        for (int k = 0; k < 16; ++k) t += part[k];
        atomicAdd(out, t * (1.0f / (float)BT));
    }
}

extern "C" void kernel_launch(void* const* d_in, const int* in_sizes, int n_in,
                              void* d_out, int out_size, void* d_ws, size_t ws_size,
                              hipStream_t stream) {
    const float*  verts = (const float*)d_in[0];   // (4,20000,3) f32
    const float4* bds   = (const float4*)d_in[1];  // (4,2048,4)  f32
    const int*    faces = (const int*)d_in[2];     // (4,40000,3) int
    const int*    p2f   = (const int*)d_in[3];     // (4,256,256,1) int
    float*        out   = (float*)d_out;

    char* ws = (char*)d_ws;
    unsigned int* visible = (unsigned int*)ws;                // 320,000 B
    unsigned int* minKeys = (unsigned int*)(ws + 320000);     //  32,768 B
    unsigned int* flags   = (unsigned int*)(ws + 352768);     //      16 B

    vis_k<<<NPIX / 256, 256, 0, stream>>>(
        p2f, faces, visible, minKeys, flags, out);
    mega_k<<<dim3(NCH, 1, BT), NTH, 0, stream>>>(
        verts, bds, visible, flags, minKeys);
    red_k<<<REDB, 1024, 0, stream>>>(minKeys, bds, flags, out);
}

// Round 12
// 94.681 us; speedup vs baseline: 1.4508x; 1.0101x over previous
//
#include <hip/hip_runtime.h>

// Problem constants: bt=4, nv=20000, nf=40000, H=W=256, S=2048
#define BT   4
#define NV   20000
#define NF   40000
#define SMP  2048
#define NPIX (BT * 256 * 256)
#define NVG  (BT * NV)            // 80000
#define NCH  128                  // vertex chunks per batch
#define NBLK (BT * NCH)           // 512 blocks = 2/CU
#define NTH  1024                 // 16 waves/block -> 8 waves/SIMD (max occ)
#define CHUNK 157                 // ceil(NV/NCH); last chunk = 61
#define P    2                    // samples per thread (1024*2 = 2048)
#define MAGIC 0x5ACE1234u         // "visible" marker; ws pre-state never matters
#define REDB 8                    // red_k blocks

// Order-preserving float<->uint encoding (q can be negative).
__device__ __forceinline__ unsigned int enc_f32(float f) {
    unsigned int u = __float_as_uint(f);
    return (u & 0x80000000u) ? ~u : (u | 0x80000000u);
}
__device__ __forceinline__ float dec_f32(unsigned int k) {
    unsigned int u = (k & 0x80000000u) ? (k & 0x7FFFFFFFu) : ~k;
    return __uint_as_float(u);
}

// 1) visibility scatter (1 pixel/thread, max occupancy for the random-access
//    latency) + side-init of minKeys/flags/out (kernel boundary orders it).
__global__ __launch_bounds__(256) void
vis_k(const int* __restrict__ p2f,
      const int* __restrict__ faces,
      unsigned int* __restrict__ visible,
      unsigned int* __restrict__ minKeys,
      unsigned int* __restrict__ flags,
      float* __restrict__ out) {
    int p = blockIdx.x * blockDim.x + threadIdx.x;   // < NPIX
    if (p < BT * SMP) minKeys[p] = 0xFFFFFFFFu;
    if (p < BT)       flags[p]   = 0u;
    if (p == BT)      out[0]     = 0.0f;             // for red_k atomicAdd

    int fi = p2f[p];
    if (fi >= 0) {
        int b    = fi / NF;
        int base = fi * 3;
        int off  = b * NV;
        visible[faces[base + 0] + off] = MAGIC;   // idempotent racy
        visible[faces[base + 1] + off] = MAGIC;
        visible[faces[base + 2] + off] = MAGIC;
    }
}

// 2) mega: pack own chunk into LDS, P=2 min loop (plain LDS broadcast; 8
//    waves/SIMD of TLP hide latency -- no register prefetch overhead),
//    filtered atomicMin on encoded keys. No fence/ticket -- visibility to
//    red_k via dispatch boundary.
__global__ __launch_bounds__(NTH) void
mega_k(const float*  __restrict__ verts,
       const float4* __restrict__ bds,
       const unsigned int* __restrict__ visible,
       unsigned int* __restrict__ flags,
       unsigned int* __restrict__ minKeys) {
    __shared__ float4 shv[CHUNK];

    const int tid = threadIdx.x;
    const int b   = blockIdx.z;
    const int c   = blockIdx.x;
    const int v0  = c * CHUNK;
    const int cntv = min(CHUNK, NV - v0);   // 157 or 61 (last)

    // pack own chunk straight into LDS; ballot-elect one flag-atomic per wave
    bool invis = false;
    if (tid < cntv) {
        int vi = b * NV + v0 + tid;
        float x = verts[3 * vi + 0];
        float y = verts[3 * vi + 1];
        float z = verts[3 * vi + 2];
        invis = (visible[vi] != MAGIC);
        float w = invis ? 1e30f : (x * x + y * y + z * z);
        shv[tid] = make_float4(-2.f * x, -2.f * y, -2.f * z, w);
    }
    {
        unsigned long long m = __ballot(invis);
        if (m != 0ull && (int)(tid & 63) == __ffsll((long long)m) - 1)
            atomicOr(&flags[b], 1u);     // <=1 device atomic per wave
    }

    float px[P], py[P], pz[P], mn[P];
    #pragma unroll
    for (int u = 0; u < P; ++u) {
        float4 p = bds[b * SMP + u * NTH + tid];
        px[u] = p.x; py[u] = p.y; pz[u] = p.z;
        mn[u] = 3.0e38f;
    }
    __syncthreads();

    #pragma unroll 8
    for (int j = 0; j < cntv; ++j) {
        float4 v = shv[j];                  // LDS broadcast (conflict-free)
        #pragma unroll
        for (int u = 0; u < P; ++u) {
            float q = fmaf(px[u], v.x,
                      fmaf(py[u], v.y,
                      fmaf(pz[u], v.z, v.w)));  // |v|^2 - 2<p,v>
            mn[u] = fminf(mn[u], q);
        }
    }

    // filtered atomicMin: keys only decrease; a (possibly stale) plain load
    // is >= the true current value, so skipping when we can't improve is
    // always safe.
    #pragma unroll
    for (int u = 0; u < P; ++u) {
        int idx = b * SMP + u * NTH + tid;
        unsigned int e = enc_f32(mn[u]);
        if (e < minKeys[idx]) atomicMin(&minKeys[idx], e);
    }
}

// 3) final: 8 blocks x 1024 threads; +|p|^2, penalty clamp, masked sum,
//    one float atomicAdd per block into pre-zeroed out[0].
__global__ __launch_bounds__(1024) void
red_k(const unsigned int* __restrict__ minKeys,
      const float4* __restrict__ bds,
      const unsigned int* __restrict__ flags,
      float* __restrict__ out) {
    const int tid = threadIdx.x;
    const int i   = blockIdx.x * 1024 + tid;     // 0..8191
    const int b   = i >> 11;
    float4 p = bds[i];
    float bs = fmaf(p.x, p.x, fmaf(p.y, p.y, p.z * p.z));
    float mnv = dec_f32(minKeys[i]) + bs;
    if (flags[b]) mnv = fminf(mnv, 1000.0f);     // exact MASK_PENALTY
    float sum = mnv * p.w;                       // p.w = sample mask

    #pragma unroll
    for (int o = 32; o > 0; o >>= 1) sum += __shfl_down(sum, o, 64);
    __shared__ float part[16];
    if ((tid & 63) == 0) part[tid >> 6] = sum;
    __syncthreads();
    if (tid == 0) {
        float t = 0.0f;
        #pragma unroll
        for (int k = 0; k < 16; ++k) t += part[k];
        atomicAdd(out, t * (1.0f / (float)BT));
    }
}

extern "C" void kernel_launch(void* const* d_in, const int* in_sizes, int n_in,
                              void* d_out, int out_size, void* d_ws, size_t ws_size,
                              hipStream_t stream) {
    const float*  verts = (const float*)d_in[0];   // (4,20000,3) f32
    const float4* bds   = (const float4*)d_in[1];  // (4,2048,4)  f32
    const int*    faces = (const int*)d_in[2];     // (4,40000,3) int
    const int*    p2f   = (const int*)d_in[3];     // (4,256,256,1) int
    float*        out   = (float*)d_out;

    char* ws = (char*)d_ws;
    unsigned int* visible = (unsigned int*)ws;                // 320,000 B
    unsigned int* minKeys = (unsigned int*)(ws + 320000);     //  32,768 B
    unsigned int* flags   = (unsigned int*)(ws + 352768);     //      16 B

    vis_k<<<NPIX / 256, 256, 0, stream>>>(
        p2f, faces, visible, minKeys, flags, out);
    mega_k<<<dim3(NCH, 1, BT), NTH, 0, stream>>>(
        verts, bds, visible, flags, minKeys);
    red_k<<<REDB, 1024, 0, stream>>>(minKeys, bds, flags, out);
}